// Round 1
// baseline (1825.247 us; speedup 1.0000x reference)
//
#include <hip/hip_runtime.h>
#include <math.h>

#define SS 2048
#define DD 1024
#define HH 16

// quantile index: floor(0.95*(S*S-1)) = floor(3984587.85)
#define K_A 3984587u
#define K_B 3984588u
#define QFRAC 0.85f

__device__ __forceinline__ unsigned sortkey(float f) {
  unsigned b = __float_as_uint(f);
  return (b & 0x80000000u) ? ~b : (b | 0x80000000u);
}
__device__ __forceinline__ float inv_sortkey(unsigned u) {
  unsigned b = (u & 0x80000000u) ? (u ^ 0x80000000u) : ~u;
  return __uint_as_float(b);
}

// ---------------- fp32 GEMM: C[2048,1024] = A[2048,1024] @ B[1024,1024] + bias ----------------
__device__ __forceinline__ void gemm128(const float* __restrict__ A,
                                        const float* __restrict__ B,
                                        const float* __restrict__ bias,
                                        float* __restrict__ C,
                                        int bm, int bn)
{
  __shared__ float As[16][128];
  __shared__ float Bs[16][128];
  const int t  = threadIdx.x;
  const int tx = t & 15, ty = t >> 4;
  const int m0 = bm * 128, n0 = bn * 128;

  float acc[8][8];
#pragma unroll
  for (int i = 0; i < 8; ++i)
#pragma unroll
    for (int j = 0; j < 8; ++j) acc[i][j] = 0.f;

  const int ar = t >> 2;          // 0..63
  const int ak = (t & 3) * 4;     // 0,4,8,12
  const int br = t >> 4;          // 0..15
  const int bc = (t & 15) * 8;    // 0..120

  for (int kb = 0; kb < 1024; kb += 16) {
    float4 a0 = *(const float4*)&A[(size_t)(m0 + ar)      * 1024 + kb + ak];
    float4 a1 = *(const float4*)&A[(size_t)(m0 + ar + 64) * 1024 + kb + ak];
    float4 b0 = *(const float4*)&B[(size_t)(kb + br) * 1024 + n0 + bc];
    float4 b1 = *(const float4*)&B[(size_t)(kb + br) * 1024 + n0 + bc + 4];
    __syncthreads();  // previous iter's LDS reads done before overwrite
    As[ak+0][ar] = a0.x; As[ak+1][ar] = a0.y; As[ak+2][ar] = a0.z; As[ak+3][ar] = a0.w;
    As[ak+0][ar+64] = a1.x; As[ak+1][ar+64] = a1.y; As[ak+2][ar+64] = a1.z; As[ak+3][ar+64] = a1.w;
    *(float4*)&Bs[br][bc]     = b0;
    *(float4*)&Bs[br][bc + 4] = b1;
    __syncthreads();
#pragma unroll
    for (int k = 0; k < 16; ++k) {
      float av[8], bv[8];
      *(float4*)&av[0] = *(const float4*)&As[k][ty*8];
      *(float4*)&av[4] = *(const float4*)&As[k][ty*8 + 4];
      *(float4*)&bv[0] = *(const float4*)&Bs[k][tx*8];
      *(float4*)&bv[4] = *(const float4*)&Bs[k][tx*8 + 4];
#pragma unroll
      for (int i = 0; i < 8; ++i)
#pragma unroll
        for (int j = 0; j < 8; ++j)
          acc[i][j] = fmaf(av[i], bv[j], acc[i][j]);
    }
  }
#pragma unroll
  for (int i = 0; i < 8; ++i) {
    const int row = m0 + ty*8 + i;
#pragma unroll
    for (int j4 = 0; j4 < 2; ++j4) {
      const int col = n0 + tx*8 + j4*4;
      float4 o;
      o.x = acc[i][j4*4+0] + bias[col+0];
      o.y = acc[i][j4*4+1] + bias[col+1];
      o.z = acc[i][j4*4+2] + bias[col+2];
      o.w = acc[i][j4*4+3] + bias[col+3];
      *(float4*)&C[(size_t)row * 1024 + col] = o;
    }
  }
}

__global__ __launch_bounds__(256) void gemm_qkv(const float* __restrict__ x,
    const float* __restrict__ Wq, const float* __restrict__ bq,
    const float* __restrict__ Wk, const float* __restrict__ bk,
    const float* __restrict__ Wv, const float* __restrict__ bv,
    float* __restrict__ Q, float* __restrict__ K, float* __restrict__ V)
{
  const int z = blockIdx.z;
  const float* W = (z == 0) ? Wq : (z == 1) ? Wk : Wv;
  const float* b = (z == 0) ? bq : (z == 1) ? bk : bv;
  float*       O = (z == 0) ? Q  : (z == 1) ? K  : V;
  gemm128(x, W, b, O, blockIdx.y, blockIdx.x);
}

__global__ __launch_bounds__(256) void gemm_single(const float* __restrict__ A,
    const float* __restrict__ W, const float* __restrict__ b, float* __restrict__ O)
{
  gemm128(A, W, b, O, blockIdx.y, blockIdx.x);
}

// ---------------- scores[hh][i][j] = (Q_h[i,:] . K_h[j,:]) / 8 ----------------
__global__ __launch_bounds__(256) void scores_kernel(const float* __restrict__ Q,
                                                     const float* __restrict__ Km,
                                                     float* __restrict__ scores,
                                                     int h0)
{
  const int bn = blockIdx.x, bm = blockIdx.y, hh = blockIdx.z;
  const int h = h0 + hh;
  __shared__ float Qs[64][128];
  __shared__ float Ks[64][128];
  const int t  = threadIdx.x;
  const int tx = t & 15, ty = t >> 4;
  const int m0 = bm * 128, n0 = bn * 128;

  const int r   = t >> 1;          // 0..127
  const int kb0 = (t & 1) * 32;    // 0 or 32
#pragma unroll
  for (int f = 0; f < 8; ++f) {
    const int kc = kb0 + f*4;
    float4 q = *(const float4*)&Q [(size_t)(m0 + r) * 1024 + h*64 + kc];
    Qs[kc+0][r] = q.x; Qs[kc+1][r] = q.y; Qs[kc+2][r] = q.z; Qs[kc+3][r] = q.w;
    float4 k = *(const float4*)&Km[(size_t)(n0 + r) * 1024 + h*64 + kc];
    Ks[kc+0][r] = k.x; Ks[kc+1][r] = k.y; Ks[kc+2][r] = k.z; Ks[kc+3][r] = k.w;
  }
  __syncthreads();

  float acc[8][8];
#pragma unroll
  for (int i = 0; i < 8; ++i)
#pragma unroll
    for (int j = 0; j < 8; ++j) acc[i][j] = 0.f;

  for (int k = 0; k < 64; ++k) {
    float av[8], bv[8];
    *(float4*)&av[0] = *(const float4*)&Qs[k][ty*8];
    *(float4*)&av[4] = *(const float4*)&Qs[k][ty*8 + 4];
    *(float4*)&bv[0] = *(const float4*)&Ks[k][tx*8];
    *(float4*)&bv[4] = *(const float4*)&Ks[k][tx*8 + 4];
#pragma unroll
    for (int i = 0; i < 8; ++i)
#pragma unroll
      for (int j = 0; j < 8; ++j)
        acc[i][j] = fmaf(av[i], bv[j], acc[i][j]);
  }

#pragma unroll
  for (int i = 0; i < 8; ++i) {
    const int row = m0 + ty*8 + i;
#pragma unroll
    for (int j4 = 0; j4 < 2; ++j4) {
      const int col = n0 + tx*8 + j4*4;
      float4 o;
      o.x = acc[i][j4*4+0] * 0.125f;
      o.y = acc[i][j4*4+1] * 0.125f;
      o.z = acc[i][j4*4+2] * 0.125f;
      o.w = acc[i][j4*4+3] * 0.125f;
      *(float4*)&scores[((size_t)hh * SS + row) * SS + col] = o;
    }
  }
}

// ---------------- radix select (exact quantile) ----------------
__global__ __launch_bounds__(256) void init_state(unsigned* __restrict__ state,
                                                  unsigned* __restrict__ hist, int cnt)
{
  const int t = threadIdx.x;
  for (int i = t; i < cnt * 512; i += 256) hist[i] = 0;
  if (t < cnt) {
    state[t*4+0] = 0u; state[t*4+1] = K_A;
    state[t*4+2] = 0u; state[t*4+3] = K_B;
  }
}

__global__ __launch_bounds__(256) void hist_pass(const float* __restrict__ scores,
                                                 unsigned* __restrict__ hist,
                                                 const unsigned* __restrict__ state,
                                                 int shift, unsigned himask)
{
  const int hh = blockIdx.y;
  __shared__ unsigned lh0[256], lh1[256];
  const int t = threadIdx.x;
  lh0[t] = 0; lh1[t] = 0;
  __syncthreads();
  const unsigned prefA = state[hh*4+0];
  const unsigned prefB = state[hh*4+2];
  const float4* base = (const float4*)(scores + (size_t)hh * SS * SS)
                       + (size_t)blockIdx.x * 16384;
  for (int i = t; i < 16384; i += 256) {
    float4 v = base[i];
    unsigned u;
    u = sortkey(v.x);
    if ((u & himask) == prefA) atomicAdd(&lh0[(u >> shift) & 255], 1u);
    if ((u & himask) == prefB) atomicAdd(&lh1[(u >> shift) & 255], 1u);
    u = sortkey(v.y);
    if ((u & himask) == prefA) atomicAdd(&lh0[(u >> shift) & 255], 1u);
    if ((u & himask) == prefB) atomicAdd(&lh1[(u >> shift) & 255], 1u);
    u = sortkey(v.z);
    if ((u & himask) == prefA) atomicAdd(&lh0[(u >> shift) & 255], 1u);
    if ((u & himask) == prefB) atomicAdd(&lh1[(u >> shift) & 255], 1u);
    u = sortkey(v.w);
    if ((u & himask) == prefA) atomicAdd(&lh0[(u >> shift) & 255], 1u);
    if ((u & himask) == prefB) atomicAdd(&lh1[(u >> shift) & 255], 1u);
  }
  __syncthreads();
  if (lh0[t]) atomicAdd(&hist[(hh*2 + 0)*256 + t], lh0[t]);
  if (lh1[t]) atomicAdd(&hist[(hh*2 + 1)*256 + t], lh1[t]);
}

__global__ __launch_bounds__(256) void scan_pass(unsigned* __restrict__ hist,
                                                 unsigned* __restrict__ state,
                                                 float* __restrict__ thr,
                                                 int shift, int cnt)
{
  const int t = threadIdx.x;
  if (t < cnt) {
    float vals[2];
    for (int tgt = 0; tgt < 2; ++tgt) {
      unsigned pref = state[t*4 + tgt*2];
      unsigned k    = state[t*4 + tgt*2 + 1];
      unsigned cum = 0; int b = 0;
      for (; b < 256; ++b) {
        unsigned c = hist[(t*2 + tgt)*256 + b];
        if (cum + c > k) break;
        cum += c;
      }
      if (b == 256) b = 255;  // defensive
      pref |= ((unsigned)b) << shift;
      k -= cum;
      state[t*4 + tgt*2]     = pref;
      state[t*4 + tgt*2 + 1] = k;
      if (shift == 0) vals[tgt] = inv_sortkey(pref);
    }
    if (shift == 0) thr[t] = vals[0] + QFRAC * (vals[1] - vals[0]);
  }
  __syncthreads();
  for (int i = t; i < cnt * 512; i += 256) hist[i] = 0;  // for next pass
}

// ---------------- masked softmax + PV for 8 query rows per block ----------------
__global__ __launch_bounds__(256) void softmax_pv(const float* __restrict__ scores,
                                                  const float* __restrict__ thrArr,
                                                  const float* __restrict__ V,
                                                  float* __restrict__ ctx,
                                                  int h0)
{
  const int qb = blockIdx.x;   // 0..255 -> rows qb*8 .. qb*8+7
  const int hh = blockIdx.y;
  const int h  = h0 + hh;
  const int t    = threadIdx.x;
  const int lane = t & 63, wave = t >> 6;
  __shared__ float P[8][2048];
  __shared__ float red[8];
  __shared__ float rowsum[8];
  __shared__ float part[2][8][64];
  const float thr = thrArr[hh];
  const float* sb = scores + ((size_t)hh * SS + (size_t)qb * 8) * SS;

  for (int r = 0; r < 8; ++r) {
    const float4* src = (const float4*)(sb + (size_t)r * SS);
    float4 v0 = src[t*2];
    float4 v1 = src[t*2 + 1];
    float m = -INFINITY;
    if (v0.x >= thr) m = fmaxf(m, v0.x);
    if (v0.y >= thr) m = fmaxf(m, v0.y);
    if (v0.z >= thr) m = fmaxf(m, v0.z);
    if (v0.w >= thr) m = fmaxf(m, v0.w);
    if (v1.x >= thr) m = fmaxf(m, v1.x);
    if (v1.y >= thr) m = fmaxf(m, v1.y);
    if (v1.z >= thr) m = fmaxf(m, v1.z);
    if (v1.w >= thr) m = fmaxf(m, v1.w);
#pragma unroll
    for (int off = 32; off; off >>= 1) m = fmaxf(m, __shfl_xor(m, off));
    if (lane == 0) red[wave] = m;
    __syncthreads();
    const float mm = fmaxf(fmaxf(red[0], red[1]), fmaxf(red[2], red[3]));
    float4 e0, e1;
    e0.x = (v0.x >= thr) ? expf(v0.x - mm) : 0.f;
    e0.y = (v0.y >= thr) ? expf(v0.y - mm) : 0.f;
    e0.z = (v0.z >= thr) ? expf(v0.z - mm) : 0.f;
    e0.w = (v0.w >= thr) ? expf(v0.w - mm) : 0.f;
    e1.x = (v1.x >= thr) ? expf(v1.x - mm) : 0.f;
    e1.y = (v1.y >= thr) ? expf(v1.y - mm) : 0.f;
    e1.z = (v1.z >= thr) ? expf(v1.z - mm) : 0.f;
    e1.w = (v1.w >= thr) ? expf(v1.w - mm) : 0.f;
    *(float4*)&P[r][t*8]     = e0;
    *(float4*)&P[r][t*8 + 4] = e1;
    float s = e0.x + e0.y + e0.z + e0.w + e1.x + e1.y + e1.z + e1.w;
#pragma unroll
    for (int off = 32; off; off >>= 1) s += __shfl_xor(s, off);
    if (lane == 0) red[4 + wave] = s;
    __syncthreads();
    if (t == 0) rowsum[r] = red[4] + red[5] + red[6] + red[7];
  }
  __syncthreads();

  // PV: thread -> dim group g (4 dims) x (row r, k-half kh)
  const int g    = t & 15;
  const int sidx = t >> 4;
  const int r    = sidx & 7;
  const int kh   = sidx >> 3;
  const float* vbase = V + h*64 + g*4;
  float ax = 0.f, ay = 0.f, az = 0.f, aw = 0.f;
  const int k0 = kh * 1024;
  for (int k4 = 0; k4 < 256; ++k4) {
    const int k = k0 + k4*4;
    float4 p4 = *(const float4*)&P[r][k];
    if (p4.x == 0.f && p4.y == 0.f && p4.z == 0.f && p4.w == 0.f) continue;
    if (p4.x != 0.f) {
      float4 v = *(const float4*)&vbase[(size_t)(k + 0) * 1024];
      ax = fmaf(p4.x, v.x, ax); ay = fmaf(p4.x, v.y, ay);
      az = fmaf(p4.x, v.z, az); aw = fmaf(p4.x, v.w, aw);
    }
    if (p4.y != 0.f) {
      float4 v = *(const float4*)&vbase[(size_t)(k + 1) * 1024];
      ax = fmaf(p4.y, v.x, ax); ay = fmaf(p4.y, v.y, ay);
      az = fmaf(p4.y, v.z, az); aw = fmaf(p4.y, v.w, aw);
    }
    if (p4.z != 0.f) {
      float4 v = *(const float4*)&vbase[(size_t)(k + 2) * 1024];
      ax = fmaf(p4.z, v.x, ax); ay = fmaf(p4.z, v.y, ay);
      az = fmaf(p4.z, v.z, az); aw = fmaf(p4.z, v.w, aw);
    }
    if (p4.w != 0.f) {
      float4 v = *(const float4*)&vbase[(size_t)(k + 3) * 1024];
      ax = fmaf(p4.w, v.x, ax); ay = fmaf(p4.w, v.y, ay);
      az = fmaf(p4.w, v.z, az); aw = fmaf(p4.w, v.w, aw);
    }
  }
  part[kh][r][g*4+0] = ax; part[kh][r][g*4+1] = ay;
  part[kh][r][g*4+2] = az; part[kh][r][g*4+3] = aw;
  __syncthreads();
  if (sidx < 8) {
    const int rr = sidx;
    const float inv = 1.f / rowsum[rr];
    float4 o;
    o.x = (part[0][rr][g*4+0] + part[1][rr][g*4+0]) * inv;
    o.y = (part[0][rr][g*4+1] + part[1][rr][g*4+1]) * inv;
    o.z = (part[0][rr][g*4+2] + part[1][rr][g*4+2]) * inv;
    o.w = (part[0][rr][g*4+3] + part[1][rr][g*4+3]) * inv;
    *(float4*)&ctx[(size_t)(qb*8 + rr) * 1024 + h*64 + g*4] = o;
  }
}

// ---------------- host ----------------
extern "C" void kernel_launch(void* const* d_in, const int* in_sizes, int n_in,
                              void* d_out, int out_size, void* d_ws, size_t ws_size,
                              hipStream_t stream)
{
  const float* x  = (const float*)d_in[0];
  const float* Wq = (const float*)d_in[1];
  const float* bq = (const float*)d_in[2];
  const float* Wk = (const float*)d_in[3];
  const float* bk = (const float*)d_in[4];
  const float* Wv = (const float*)d_in[5];
  const float* bv = (const float*)d_in[6];
  const float* Wo = (const float*)d_in[7];
  const float* bo = (const float*)d_in[8];
  float* out = (float*)d_out;
  char*  ws  = (char*)d_ws;

  const size_t SD = (size_t)SS * DD * sizeof(float);  // 8 MiB
  float*    Q     = (float*)(ws + 0*SD);
  float*    K     = (float*)(ws + 1*SD);
  float*    V     = (float*)(ws + 2*SD);
  float*    ctx   = (float*)(ws + 3*SD);
  unsigned* state = (unsigned*)(ws + 4*SD);
  float*    thr   = (float*)(ws + 4*SD + 4096);
  unsigned* hist  = (unsigned*)(ws + 4*SD + 8192);     // 32 KiB
  const size_t off_scores = 4*SD + 65536;
  float* scores = (float*)(ws + off_scores);
  const size_t perHead = (size_t)SS * SS * sizeof(float);  // 16 MiB

  int CH = 1;
  if (ws_size > off_scores + perHead)
    CH = (int)((ws_size - off_scores) / perHead);
  if (CH > HH) CH = HH;
  if (CH < 1)  CH = 1;

  gemm_qkv<<<dim3(8, 16, 3), 256, 0, stream>>>(x, Wq, bq, Wk, bk, Wv, bv, Q, K, V);

  for (int h0 = 0; h0 < HH; h0 += CH) {
    const int cnt = (HH - h0 < CH) ? (HH - h0) : CH;
    scores_kernel<<<dim3(16, 16, cnt), 256, 0, stream>>>(Q, K, scores, h0);
    init_state<<<1, 256, 0, stream>>>(state, hist, cnt);
    for (int p = 0; p < 4; ++p) {
      const int shift = 24 - 8*p;
      const unsigned himask = (p == 0) ? 0u : (0xFFFFFFFFu << (shift + 8));
      hist_pass<<<dim3(64, cnt), 256, 0, stream>>>(scores, hist, state, shift, himask);
      scan_pass<<<1, 256, 0, stream>>>(hist, state, thr, shift, cnt);
    }
    softmax_pv<<<dim3(256, cnt), 256, 0, stream>>>(scores, thr, V, ctx, h0);
  }

  gemm_single<<<dim3(8, 16), 256, 0, stream>>>(ctx, Wo, bo, out);
}

// Round 3
// 1240.598 us; speedup vs baseline: 1.4713x; 1.4713x over previous
//
#include <hip/hip_runtime.h>
#include <math.h>

#define SS 2048
#define DD 1024
#define HH 16

// quantile index: floor(0.95*(S*S-1)) = floor(3984587.85)
#define K_A 3984587u
#define K_B 3984588u
#define QFRAC 0.85f

__device__ __forceinline__ unsigned sortkey(float f) {
  unsigned b = __float_as_uint(f);
  return (b & 0x80000000u) ? ~b : (b | 0x80000000u);
}
__device__ __forceinline__ float inv_sortkey(unsigned u) {
  unsigned b = (u & 0x80000000u) ? (u ^ 0x80000000u) : ~u;
  return __uint_as_float(b);
}

// ---------------- fp32 GEMM: C[2048,1024] = A[2048,1024] @ B[1024,1024] + bias ----------------
__device__ __forceinline__ void gemm128(const float* __restrict__ A,
                                        const float* __restrict__ B,
                                        const float* __restrict__ bias,
                                        float* __restrict__ C,
                                        int bm, int bn)
{
  __shared__ float As[16][128];
  __shared__ float Bs[16][128];
  const int t  = threadIdx.x;
  const int tx = t & 15, ty = t >> 4;
  const int m0 = bm * 128, n0 = bn * 128;

  float acc[8][8];
#pragma unroll
  for (int i = 0; i < 8; ++i)
#pragma unroll
    for (int j = 0; j < 8; ++j) acc[i][j] = 0.f;

  const int ar = t >> 2;          // 0..63
  const int ak = (t & 3) * 4;     // 0,4,8,12
  const int br = t >> 4;          // 0..15
  const int bc = (t & 15) * 8;    // 0..120

  for (int kb = 0; kb < 1024; kb += 16) {
    float4 a0 = *(const float4*)&A[(size_t)(m0 + ar)      * 1024 + kb + ak];
    float4 a1 = *(const float4*)&A[(size_t)(m0 + ar + 64) * 1024 + kb + ak];
    float4 b0 = *(const float4*)&B[(size_t)(kb + br) * 1024 + n0 + bc];
    float4 b1 = *(const float4*)&B[(size_t)(kb + br) * 1024 + n0 + bc + 4];
    __syncthreads();  // previous iter's LDS reads done before overwrite
    As[ak+0][ar] = a0.x; As[ak+1][ar] = a0.y; As[ak+2][ar] = a0.z; As[ak+3][ar] = a0.w;
    As[ak+0][ar+64] = a1.x; As[ak+1][ar+64] = a1.y; As[ak+2][ar+64] = a1.z; As[ak+3][ar+64] = a1.w;
    *(float4*)&Bs[br][bc]     = b0;
    *(float4*)&Bs[br][bc + 4] = b1;
    __syncthreads();
#pragma unroll
    for (int k = 0; k < 16; ++k) {
      float av[8], bv[8];
      *(float4*)&av[0] = *(const float4*)&As[k][ty*8];
      *(float4*)&av[4] = *(const float4*)&As[k][ty*8 + 4];
      *(float4*)&bv[0] = *(const float4*)&Bs[k][tx*8];
      *(float4*)&bv[4] = *(const float4*)&Bs[k][tx*8 + 4];
#pragma unroll
      for (int i = 0; i < 8; ++i)
#pragma unroll
        for (int j = 0; j < 8; ++j)
          acc[i][j] = fmaf(av[i], bv[j], acc[i][j]);
    }
  }
#pragma unroll
  for (int i = 0; i < 8; ++i) {
    const int row = m0 + ty*8 + i;
#pragma unroll
    for (int j4 = 0; j4 < 2; ++j4) {
      const int col = n0 + tx*8 + j4*4;
      float4 o;
      o.x = acc[i][j4*4+0] + bias[col+0];
      o.y = acc[i][j4*4+1] + bias[col+1];
      o.z = acc[i][j4*4+2] + bias[col+2];
      o.w = acc[i][j4*4+3] + bias[col+3];
      *(float4*)&C[(size_t)row * 1024 + col] = o;
    }
  }
}

__global__ __launch_bounds__(256) void gemm_qkv(const float* __restrict__ x,
    const float* __restrict__ Wq, const float* __restrict__ bq,
    const float* __restrict__ Wk, const float* __restrict__ bk,
    const float* __restrict__ Wv, const float* __restrict__ bv,
    float* __restrict__ Q, float* __restrict__ K, float* __restrict__ V)
{
  const int z = blockIdx.z;
  const float* W = (z == 0) ? Wq : (z == 1) ? Wk : Wv;
  const float* b = (z == 0) ? bq : (z == 1) ? bk : bv;
  float*       O = (z == 0) ? Q  : (z == 1) ? K  : V;
  gemm128(x, W, b, O, blockIdx.y, blockIdx.x);
}

__global__ __launch_bounds__(256) void gemm_single(const float* __restrict__ A,
    const float* __restrict__ W, const float* __restrict__ b, float* __restrict__ O)
{
  gemm128(A, W, b, O, blockIdx.y, blockIdx.x);
}

// ---------------- scores[hh][i][j] = (Q_h[i,:] . K_h[j,:]) / 8 ----------------
__global__ __launch_bounds__(256) void scores_kernel(const float* __restrict__ Q,
                                                     const float* __restrict__ Km,
                                                     float* __restrict__ scores,
                                                     int h0)
{
  const int bn = blockIdx.x, bm = blockIdx.y, hh = blockIdx.z;
  const int h = h0 + hh;
  __shared__ float Qs[64][128];
  __shared__ float Ks[64][128];
  const int t  = threadIdx.x;
  const int tx = t & 15, ty = t >> 4;
  const int m0 = bm * 128, n0 = bn * 128;

  const int r   = t >> 1;          // 0..127
  const int kb0 = (t & 1) * 32;    // 0 or 32
#pragma unroll
  for (int f = 0; f < 8; ++f) {
    const int kc = kb0 + f*4;
    float4 q = *(const float4*)&Q [(size_t)(m0 + r) * 1024 + h*64 + kc];
    Qs[kc+0][r] = q.x; Qs[kc+1][r] = q.y; Qs[kc+2][r] = q.z; Qs[kc+3][r] = q.w;
    float4 k = *(const float4*)&Km[(size_t)(n0 + r) * 1024 + h*64 + kc];
    Ks[kc+0][r] = k.x; Ks[kc+1][r] = k.y; Ks[kc+2][r] = k.z; Ks[kc+3][r] = k.w;
  }
  __syncthreads();

  float acc[8][8];
#pragma unroll
  for (int i = 0; i < 8; ++i)
#pragma unroll
    for (int j = 0; j < 8; ++j) acc[i][j] = 0.f;

  for (int k = 0; k < 64; ++k) {
    float av[8], bv[8];
    *(float4*)&av[0] = *(const float4*)&Qs[k][ty*8];
    *(float4*)&av[4] = *(const float4*)&Qs[k][ty*8 + 4];
    *(float4*)&bv[0] = *(const float4*)&Ks[k][tx*8];
    *(float4*)&bv[4] = *(const float4*)&Ks[k][tx*8 + 4];
#pragma unroll
    for (int i = 0; i < 8; ++i)
#pragma unroll
      for (int j = 0; j < 8; ++j)
        acc[i][j] = fmaf(av[i], bv[j], acc[i][j]);
  }

#pragma unroll
  for (int i = 0; i < 8; ++i) {
    const int row = m0 + ty*8 + i;
#pragma unroll
    for (int j4 = 0; j4 < 2; ++j4) {
      const int col = n0 + tx*8 + j4*4;
      float4 o;
      o.x = acc[i][j4*4+0] * 0.125f;
      o.y = acc[i][j4*4+1] * 0.125f;
      o.z = acc[i][j4*4+2] * 0.125f;
      o.w = acc[i][j4*4+3] * 0.125f;
      *(float4*)&scores[((size_t)hh * SS + row) * SS + col] = o;
    }
  }
}

// ---------------- radix select (exact quantile) ----------------
__global__ __launch_bounds__(256) void init_state(unsigned* __restrict__ state,
                                                  unsigned* __restrict__ hist, int cnt)
{
  const int t = threadIdx.x;
  for (int i = t; i < HH * 512; i += 256) hist[i] = 0;   // full clear, cnt-independent
  if (t < cnt) {
    state[t*4+0] = 0u; state[t*4+1] = K_A;
    state[t*4+2] = 0u; state[t*4+3] = K_B;
  }
}

__global__ __launch_bounds__(256) void hist_pass(const float* __restrict__ scores,
                                                 unsigned* __restrict__ hist,
                                                 const unsigned* __restrict__ state,
                                                 int shift, unsigned himask)
{
  const int hh = blockIdx.y;
  __shared__ unsigned lh0[256], lh1[256];
  const int t = threadIdx.x;
  lh0[t] = 0; lh1[t] = 0;
  __syncthreads();
  const unsigned prefA = state[hh*4+0];
  const unsigned prefB = state[hh*4+2];
  const float4* base = (const float4*)(scores + (size_t)hh * SS * SS)
                       + (size_t)blockIdx.x * 16384;
  for (int i = t; i < 16384; i += 256) {
    float4 v = base[i];
    unsigned u;
    u = sortkey(v.x);
    if ((u & himask) == prefA) atomicAdd(&lh0[(u >> shift) & 255], 1u);
    if ((u & himask) == prefB) atomicAdd(&lh1[(u >> shift) & 255], 1u);
    u = sortkey(v.y);
    if ((u & himask) == prefA) atomicAdd(&lh0[(u >> shift) & 255], 1u);
    if ((u & himask) == prefB) atomicAdd(&lh1[(u >> shift) & 255], 1u);
    u = sortkey(v.z);
    if ((u & himask) == prefA) atomicAdd(&lh0[(u >> shift) & 255], 1u);
    if ((u & himask) == prefB) atomicAdd(&lh1[(u >> shift) & 255], 1u);
    u = sortkey(v.w);
    if ((u & himask) == prefA) atomicAdd(&lh0[(u >> shift) & 255], 1u);
    if ((u & himask) == prefB) atomicAdd(&lh1[(u >> shift) & 255], 1u);
  }
  __syncthreads();
  if (lh0[t]) atomicAdd(&hist[(hh*2 + 0)*256 + t], lh0[t]);
  if (lh1[t]) atomicAdd(&hist[(hh*2 + 1)*256 + t], lh1[t]);
}

__global__ __launch_bounds__(256) void scan_pass(unsigned* __restrict__ hist,
                                                 unsigned* __restrict__ state,
                                                 float* __restrict__ thr,
                                                 int shift, int cnt)
{
  const int t = threadIdx.x;
  if (t < cnt) {
    float vals[2];
    for (int tgt = 0; tgt < 2; ++tgt) {
      unsigned pref = state[t*4 + tgt*2];
      unsigned k    = state[t*4 + tgt*2 + 1];
      unsigned cum = 0; int b = 0;
      for (; b < 256; ++b) {
        unsigned c = hist[(t*2 + tgt)*256 + b];
        if (cum + c > k) break;
        cum += c;
      }
      if (b == 256) b = 255;  // defensive
      pref |= ((unsigned)b) << shift;
      k -= cum;
      state[t*4 + tgt*2]     = pref;
      state[t*4 + tgt*2 + 1] = k;
      if (shift == 0) vals[tgt] = inv_sortkey(pref);
    }
    if (shift == 0) thr[t] = vals[0] + QFRAC * (vals[1] - vals[0]);
  }
  __syncthreads();
  for (int i = t; i < HH * 512; i += 256) hist[i] = 0;  // full clear for next pass
}

// ---------------- wave-per-row masked softmax + ballot-compacted sparse PV ----------------
__global__ __launch_bounds__(256) void softmax_pv2(const float* __restrict__ scores,
                                                   const float* __restrict__ thrArr,
                                                   const float* __restrict__ V,
                                                   float* __restrict__ ctx,
                                                   int h0)
{
  const int wave = threadIdx.x >> 6;
  const int lane = threadIdx.x & 63;
  const int row  = blockIdx.x * 4 + wave;
  const int hh   = blockIdx.y;
  const int h    = h0 + hh;
  const float thr = thrArr[hh];
  const float* __restrict__ srow = scores + ((size_t)hh * SS + row) * SS;

  // load 32 elements per lane; lane owns k = t*64 + lane (coalesced dword loads)
  float p[32];
#pragma unroll
  for (int t = 0; t < 32; ++t) p[t] = srow[t*64 + lane];

  // masked row max
  float m = -INFINITY;
#pragma unroll
  for (int t = 0; t < 32; ++t)
    if (p[t] >= thr) m = fmaxf(m, p[t]);
#pragma unroll
  for (int off = 32; off; off >>= 1) m = fmaxf(m, __shfl_xor(m, off));

  // exp + rowsum (exp only affects weights, not mask membership)
  float sum = 0.f;
#pragma unroll
  for (int t = 0; t < 32; ++t) {
    float e = (p[t] >= thr) ? __expf(p[t] - m) : 0.f;
    p[t] = e;
    sum += e;
  }
#pragma unroll
  for (int off = 32; off; off >>= 1) sum += __shfl_xor(sum, off);

  // sparse PV: per 64-tile ballot, iterate set bits (wave-uniform), 2 loads in flight
  float acc0 = 0.f, acc1 = 0.f;
  const float* __restrict__ vcol = V + h*64 + lane;
#pragma unroll
  for (int t = 0; t < 32; ++t) {
    unsigned long long mk = __ballot(p[t] != 0.f);
    const float* __restrict__ vt = vcol + (size_t)t * 64 * 1024;
    while (mk) {
      int b0 = __ffsll(mk) - 1; mk &= mk - 1;
      if (mk) {
        int b1 = __ffsll(mk) - 1; mk &= mk - 1;
        float va = vt[(size_t)b0 * 1024];
        float vb = vt[(size_t)b1 * 1024];
        acc0 = fmaf(__shfl(p[t], b0), va, acc0);
        acc1 = fmaf(__shfl(p[t], b1), vb, acc1);
      } else {
        acc0 = fmaf(__shfl(p[t], b0), vt[(size_t)b0 * 1024], acc0);
      }
    }
  }
  ctx[(size_t)row * 1024 + h*64 + lane] = (acc0 + acc1) / sum;
}

// ---------------- host ----------------
extern "C" void kernel_launch(void* const* d_in, const int* in_sizes, int n_in,
                              void* d_out, int out_size, void* d_ws, size_t ws_size,
                              hipStream_t stream)
{
  const float* x  = (const float*)d_in[0];
  const float* Wq = (const float*)d_in[1];
  const float* bq = (const float*)d_in[2];
  const float* Wk = (const float*)d_in[3];
  const float* bk = (const float*)d_in[4];
  const float* Wv = (const float*)d_in[5];
  const float* bv = (const float*)d_in[6];
  const float* Wo = (const float*)d_in[7];
  const float* bo = (const float*)d_in[8];
  float* out = (float*)d_out;
  char*  ws  = (char*)d_ws;

  const size_t SD = (size_t)SS * DD * sizeof(float);  // 8 MiB
  float*    Q     = (float*)(ws + 0*SD);
  float*    K     = (float*)(ws + 1*SD);
  float*    V     = (float*)(ws + 2*SD);
  float*    ctx   = (float*)(ws + 3*SD);
  unsigned* state = (unsigned*)(ws + 4*SD);
  float*    thr   = (float*)(ws + 4*SD + 4096);
  unsigned* hist  = (unsigned*)(ws + 4*SD + 8192);     // 32 KiB
  const size_t off_scores = 4*SD + 65536;
  float* scores = (float*)(ws + off_scores);
  const size_t perHead = (size_t)SS * SS * sizeof(float);  // 16 MiB

  int CH = 1;
  if (ws_size > off_scores + perHead)
    CH = (int)((ws_size - off_scores) / perHead);
  if (CH > HH) CH = HH;
  if (CH < 1)  CH = 1;

  gemm_qkv<<<dim3(8, 16, 3), 256, 0, stream>>>(x, Wq, bq, Wk, bk, Wv, bv, Q, K, V);

  for (int h0 = 0; h0 < HH; h0 += CH) {
    const int cnt = (HH - h0 < CH) ? (HH - h0) : CH;
    scores_kernel<<<dim3(16, 16, cnt), 256, 0, stream>>>(Q, K, scores, h0);
    init_state<<<1, 256, 0, stream>>>(state, hist, cnt);
    for (int p = 0; p < 4; ++p) {
      const int shift = 24 - 8*p;
      const unsigned himask = (p == 0) ? 0u : (0xFFFFFFFFu << (shift + 8));
      hist_pass<<<dim3(64, cnt), 256, 0, stream>>>(scores, hist, state, shift, himask);
      scan_pass<<<1, 256, 0, stream>>>(hist, state, thr, shift, cnt);
    }
    softmax_pv2<<<dim3(SS/4, cnt), 256, 0, stream>>>(scores, thr, V, ctx, h0);
  }

  gemm_single<<<dim3(8, 16), 256, 0, stream>>>(ctx, Wo, bo, out);
}